// Round 1
// baseline (2456.698 us; speedup 1.0000x reference)
//
#include <hip/hip_runtime.h>

#define HID 64
#define FEAT 10

// ---------- degree / normalization ----------
__global__ void deg_kernel(const int* __restrict__ dst, float* __restrict__ deg, int E) {
    int e = blockIdx.x * 256 + threadIdx.x;
    if (e < E) atomicAdd(&deg[dst[e]], 1.0f);
}

__global__ void dinv_kernel(float* deg, int N) {
    int i = blockIdx.x * 256 + threadIdx.x;
    if (i < N) deg[i] = rsqrtf(deg[i] + 1.0f);   // in-place: deg -> dinv
}

__global__ void norm_edge_kernel(const int* __restrict__ src, const int* __restrict__ dst,
                                 const float* __restrict__ dinv, float* __restrict__ ne, int E) {
    int e = blockIdx.x * 256 + threadIdx.x;
    if (e < E) ne[e] = dinv[src[e]] * dinv[dst[e]];
}

// ---------- per-layer dense matmul: hw = h_in @ W ; agg = hw * dinv^2 (self loop) ----------
// block = 256 threads handles 16 nodes x 64 cols (4 outputs/thread). W staged in LDS.
__global__ void gcn_matmul(const float* __restrict__ h_in, const float* __restrict__ W,
                           const float* __restrict__ dinv,
                           float* __restrict__ hw, float* __restrict__ agg,
                           int N, int Fin) {
    __shared__ float sW[64 * 64];
    __shared__ float sH[16 * 64];
    int t = threadIdx.x;
    for (int i = t; i < Fin * 64; i += 256) sW[i] = W[i];
    int node0 = blockIdx.x * 16;
    for (int i = t; i < 16 * Fin; i += 256) {
        int r = i / Fin, k = i - r * Fin;
        int node = node0 + r;
        sH[r * Fin + k] = (node < N) ? h_in[(size_t)node * Fin + k] : 0.0f;
    }
    __syncthreads();
    int c = t & 63;
    for (int r = t >> 6; r < 16; r += 4) {
        int node = node0 + r;
        if (node >= N) continue;
        float acc = 0.0f;
        for (int k = 0; k < Fin; k++) acc += sH[r * Fin + k] * sW[k * 64 + c];
        float di = dinv[node];
        hw[(size_t)node * 64 + c]  = acc;
        agg[(size_t)node * 64 + c] = acc * di * di;
    }
}

// ---------- edge aggregation: agg[dst] += hw[src] * norm_edge ----------
// 16 threads per edge, float4 gather per thread, 4 scalar atomics.
__global__ void edge_agg(const int* __restrict__ src, const int* __restrict__ dst,
                         const float* __restrict__ ne, const float* __restrict__ hw,
                         float* __restrict__ agg, int E) {
    int gid = blockIdx.x * 256 + threadIdx.x;
    int e = gid >> 4;
    if (e >= E) return;
    int q = gid & 15;
    int s = src[e], d = dst[e];
    float w = ne[e];
    const float4 v = *(const float4*)(hw + (size_t)s * 64 + q * 4);
    float* o = agg + (size_t)d * 64 + q * 4;
    atomicAdd(o + 0, v.x * w);
    atomicAdd(o + 1, v.y * w);
    atomicAdd(o + 2, v.z * w);
    atomicAdd(o + 3, v.w * w);
}

// ---------- bias + relu (in place); optionally accumulate column sums for global mean pool ----------
__global__ void bias_relu(float* __restrict__ agg, const float* __restrict__ b,
                          int N, float* __restrict__ g_sum, int do_gsum) {
    int idx = blockIdx.x * 256 + threadIdx.x;
    int total = N * 64;
    float v = 0.0f;
    if (idx < total) {
        int c = idx & 63;
        v = agg[idx] + b[c];
        v = fmaxf(v, 0.0f);
        agg[idx] = v;
    }
    if (do_gsum) {
        __shared__ float lds[256];
        lds[threadIdx.x] = v;
        __syncthreads();
        if (threadIdx.x < 64) {
            // columns of lds[t], lds[t+64], ... are all == t (256 % 64 == 0)
            float s = lds[threadIdx.x] + lds[threadIdx.x + 64] +
                      lds[threadIdx.x + 128] + lds[threadIdx.x + 192];
            atomicAdd(&g_sum[threadIdx.x], s);
        }
    }
}

// ---------- head: sheet pooling + geo MLP + fusion + q MLP, one block per sheet ----------
__global__ void final_kernel(const float* __restrict__ h3, const int* __restrict__ sheet_idx,
                             const float* __restrict__ sheet_feat, const float* __restrict__ g_sum,
                             const float* __restrict__ gW1, const float* __restrict__ gb1,
                             const float* __restrict__ gW2, const float* __restrict__ gb2,
                             const float* __restrict__ fW,  const float* __restrict__ fb,
                             const float* __restrict__ qW1, const float* __restrict__ qb1,
                             const float* __restrict__ qW2, const float* __restrict__ qb2,
                             float* __restrict__ out, int N, int L) {
    int s = blockIdx.x, t = threadIdx.x;
    __shared__ float red[256];
    __shared__ float semb[64];
    __shared__ float geoh[64];
    __shared__ float geo[64];
    __shared__ float hq[128];   // [fused(0..63) | g_emb(64..127)]
    int c = t & 63, jg = t >> 6;
    float acc = 0.0f;
    for (int j = jg; j < L; j += 4) {
        int node = sheet_idx[s * L + j];
        acc += h3[(size_t)node * 64 + c];
    }
    red[t] = acc;
    __syncthreads();
    if (t < 64) {
        semb[t] = (red[t] + red[t + 64] + red[t + 128] + red[t + 192]) / (float)L;
        hq[64 + t] = g_sum[t] / (float)N;
        float a = gb1[t];
        #pragma unroll
        for (int k = 0; k < FEAT; k++) a += sheet_feat[s * FEAT + k] * gW1[k * 64 + t];
        geoh[t] = fmaxf(a, 0.0f);
    }
    __syncthreads();
    if (t < 64) {
        float a = gb2[t];
        for (int k = 0; k < 64; k++) a += geoh[k] * gW2[k * 64 + t];
        geo[t] = a;                                   // no relu on geo output
    }
    __syncthreads();
    if (t < 64) {
        float a = fb[t];
        for (int k = 0; k < 64; k++) a += semb[k] * fW[k * 64 + t];
        for (int k = 0; k < 64; k++) a += geo[k]  * fW[(64 + k) * 64 + t];
        hq[t] = fmaxf(a, 0.0f);                       // fused
    }
    __syncthreads();
    float q = 0.0f;
    if (t < 64) {
        float a = qb1[t];
        for (int k = 0; k < 128; k++) a += hq[k] * qW1[k * 64 + t];
        a = fmaxf(a, 0.0f);
        q = a * qW2[t];
        for (int off = 32; off > 0; off >>= 1) q += __shfl_down(q, off, 64);
        if (t == 0) out[s] = q + qb2[0];
    }
}

extern "C" void kernel_launch(void* const* d_in, const int* in_sizes, int n_in,
                              void* d_out, int out_size, void* d_ws, size_t ws_size,
                              hipStream_t stream) {
    const float* x          = (const float*)d_in[0];
    const int*   edge       = (const int*)d_in[1];     // [2, E] row-major: src then dst
    const int*   sheet_idx  = (const int*)d_in[3];
    const float* sheet_feat = (const float*)d_in[4];
    const float* W1 = (const float*)d_in[5];  const float* b1 = (const float*)d_in[6];
    const float* W2 = (const float*)d_in[7];  const float* b2 = (const float*)d_in[8];
    const float* W3 = (const float*)d_in[9];  const float* b3 = (const float*)d_in[10];
    const float* gW1 = (const float*)d_in[11]; const float* gb1 = (const float*)d_in[12];
    const float* gW2 = (const float*)d_in[13]; const float* gb2 = (const float*)d_in[14];
    const float* fW  = (const float*)d_in[15]; const float* fb  = (const float*)d_in[16];
    const float* qW1 = (const float*)d_in[17]; const float* qb1 = (const float*)d_in[18];
    const float* qW2 = (const float*)d_in[19]; const float* qb2 = (const float*)d_in[20];
    float* out = (float*)d_out;

    int N = in_sizes[2];            // 50000 (batch array length)
    int E = in_sizes[1] / 2;        // 800000
    int S = in_sizes[4] / FEAT;     // 256 sheets
    int L = in_sizes[3] / S;        // 128 nodes per sheet

    float* ws    = (float*)d_ws;
    float* deg   = ws;                      // N (becomes dinv)
    float* ne    = deg + N;                 // E
    float* g_sum = ne + E;                  // 64
    float* buf0  = g_sum + 64;              // N*64  (hw scratch)
    float* buf1  = buf0 + (size_t)N * 64;   // N*64
    float* buf2  = buf1 + (size_t)N * 64;   // N*64

    hipMemsetAsync(deg, 0, (size_t)N * sizeof(float), stream);
    hipMemsetAsync(g_sum, 0, 64 * sizeof(float), stream);

    const int* src = edge;
    const int* dst = edge + E;

    int gE  = (E + 255) / 256;
    int gN  = (N + 255) / 256;
    int gMM = (N + 15) / 16;
    int gEA = (int)(((long long)E * 16 + 255) / 256);
    int gBR = (int)(((long long)N * 64 + 255) / 256);

    deg_kernel<<<gE, 256, 0, stream>>>(dst, deg, E);
    dinv_kernel<<<gN, 256, 0, stream>>>(deg, N);
    norm_edge_kernel<<<gE, 256, 0, stream>>>(src, dst, deg, ne, E);

    // layer 1: h_in = x (FEAT wide)
    gcn_matmul<<<gMM, 256, 0, stream>>>(x, W1, deg, buf0, buf1, N, FEAT);
    edge_agg<<<gEA, 256, 0, stream>>>(src, dst, ne, buf0, buf1, E);
    bias_relu<<<gBR, 256, 0, stream>>>(buf1, b1, N, nullptr, 0);

    // layer 2: h_in = buf1
    gcn_matmul<<<gMM, 256, 0, stream>>>(buf1, W2, deg, buf0, buf2, N, HID);
    edge_agg<<<gEA, 256, 0, stream>>>(src, dst, ne, buf0, buf2, E);
    bias_relu<<<gBR, 256, 0, stream>>>(buf2, b2, N, nullptr, 0);

    // layer 3: h_in = buf2, h3 -> buf1, accumulate g_sum
    gcn_matmul<<<gMM, 256, 0, stream>>>(buf2, W3, deg, buf0, buf1, N, HID);
    edge_agg<<<gEA, 256, 0, stream>>>(src, dst, ne, buf0, buf1, E);
    bias_relu<<<gBR, 256, 0, stream>>>(buf1, b3, N, g_sum, 1);

    final_kernel<<<S, 256, 0, stream>>>(buf1, sheet_idx, sheet_feat, g_sum,
                                        gW1, gb1, gW2, gb2, fW, fb,
                                        qW1, qb1, qW2, qb2, out, N, L);
}

// Round 2
// 486.732 us; speedup vs baseline: 5.0473x; 5.0473x over previous
//
#include <hip/hip_runtime.h>

#define HID 64
#define FEAT 10

// ================= CSR build =================

__global__ void hist_kernel(const int* __restrict__ dst, int* __restrict__ cnt, int E) {
    int e = blockIdx.x * 256 + threadIdx.x;
    if (e < E) atomicAdd(&cnt[dst[e]], 1);
}

__global__ void dinv_kernel(const int* __restrict__ cnt, float* __restrict__ dinv, int N) {
    int i = blockIdx.x * 256 + threadIdx.x;
    if (i < N) dinv[i] = rsqrtf((float)cnt[i] + 1.0f);
}

// per-block partial sums of cnt (256 elems per block)
__global__ void bsum_kernel(const int* __restrict__ cnt, int* __restrict__ bsum, int N) {
    __shared__ int lds[256];
    int i = blockIdx.x * 256 + threadIdx.x;
    lds[threadIdx.x] = (i < N) ? cnt[i] : 0;
    __syncthreads();
    for (int off = 128; off > 0; off >>= 1) {
        if (threadIdx.x < off) lds[threadIdx.x] += lds[threadIdx.x + off];
        __syncthreads();
    }
    if (threadIdx.x == 0) bsum[blockIdx.x] = lds[0];
}

// single block: exclusive scan of bsum[nb] in place; row_ptr[N] = total
__global__ void bscan_kernel(int* __restrict__ bsum, int* __restrict__ row_ptr, int nb, int N) {
    __shared__ int lds[256];
    int t = threadIdx.x;
    int v = (t < nb) ? bsum[t] : 0;
    lds[t] = v;
    __syncthreads();
    for (int off = 1; off < 256; off <<= 1) {
        int a = lds[t];
        int b = (t >= off) ? lds[t - off] : 0;
        __syncthreads();
        lds[t] = a + b;
        __syncthreads();
    }
    if (t < nb) bsum[t] = lds[t] - v;            // exclusive
    if (t == 0) row_ptr[N] = lds[255];           // total == E
}

// per-block: exclusive scan within chunk + block offset -> row_ptr, cursor
__global__ void chunk_scan_kernel(const int* __restrict__ cnt, const int* __restrict__ bsum,
                                  int* __restrict__ row_ptr, int* __restrict__ cursor, int N) {
    __shared__ int lds[256];
    int t = threadIdx.x;
    int i = blockIdx.x * 256 + t;
    int v = (i < N) ? cnt[i] : 0;
    lds[t] = v;
    __syncthreads();
    for (int off = 1; off < 256; off <<= 1) {
        int a = lds[t];
        int b = (t >= off) ? lds[t - off] : 0;
        __syncthreads();
        lds[t] = a + b;
        __syncthreads();
    }
    if (i < N) {
        int val = bsum[blockIdx.x] + lds[t] - v;
        row_ptr[i] = val;
        cursor[i]  = val;
    }
}

__global__ void scatter_kernel(const int* __restrict__ src, const int* __restrict__ dst,
                               const float* __restrict__ dinv, int* __restrict__ cursor,
                               int* __restrict__ csr_src, float* __restrict__ csr_w, int E) {
    int e = blockIdx.x * 256 + threadIdx.x;
    if (e >= E) return;
    int s = src[e], d = dst[e];
    int pos = atomicAdd(&cursor[d], 1);
    csr_src[pos] = s;
    csr_w[pos]   = dinv[s] * dinv[d];
}

// ================= GCN layers =================

// hw = h_in @ W. block = 256 threads: 16 nodes x 64 cols (4 rows/thread). W in LDS.
__global__ void gcn_matmul(const float* __restrict__ h_in, const float* __restrict__ W,
                           float* __restrict__ hw, int N, int Fin) {
    __shared__ float sW[64 * 64];
    __shared__ float sH[16 * 64];
    int t = threadIdx.x;
    for (int i = t; i < Fin * 64; i += 256) sW[i] = W[i];
    int node0 = blockIdx.x * 16;
    for (int i = t; i < 16 * Fin; i += 256) {
        int r = i / Fin, k = i - r * Fin;
        int node = node0 + r;
        sH[r * Fin + k] = (node < N) ? h_in[(size_t)node * Fin + k] : 0.0f;
    }
    __syncthreads();
    int c = t & 63;
    for (int r = t >> 6; r < 16; r += 4) {
        int node = node0 + r;
        if (node >= N) continue;
        float acc = 0.0f;
        for (int k = 0; k < Fin; k++) acc += sH[r * Fin + k] * sW[k * 64 + c];
        hw[(size_t)node * 64 + c] = acc;
    }
}

// out[n] = relu( hw[n]*dinv[n]^2 + sum_{e in CSR[n]} hw[src_e]*w_e + b )
// 16 lanes per node (float4 per lane), 16 nodes per block.
__global__ void gather_agg(const int* __restrict__ row_ptr, const int* __restrict__ csr_src,
                           const float* __restrict__ csr_w, const float* __restrict__ hw,
                           const float* __restrict__ dinv, const float* __restrict__ b,
                           float* __restrict__ out, float* __restrict__ gsum,
                           int N, int do_gsum) {
    int t = threadIdx.x;
    int node = blockIdx.x * 16 + (t >> 4);
    int q = t & 15;
    int c0 = q * 4;
    float4 acc = make_float4(0.f, 0.f, 0.f, 0.f);
    if (node < N) {
        float di = dinv[node];
        float wself = di * di;
        float4 v = *(const float4*)(hw + (size_t)node * 64 + c0);
        acc.x = v.x * wself; acc.y = v.y * wself; acc.z = v.z * wself; acc.w = v.w * wself;
        int i0 = row_ptr[node], i1 = row_ptr[node + 1];
        for (int i = i0; i < i1; i++) {
            int s = csr_src[i];
            float w = csr_w[i];
            float4 u = *(const float4*)(hw + (size_t)s * 64 + c0);
            acc.x += u.x * w; acc.y += u.y * w; acc.z += u.z * w; acc.w += u.w * w;
        }
        const float4 bb = *(const float4*)(b + c0);
        acc.x = fmaxf(acc.x + bb.x, 0.f);
        acc.y = fmaxf(acc.y + bb.y, 0.f);
        acc.z = fmaxf(acc.z + bb.z, 0.f);
        acc.w = fmaxf(acc.w + bb.w, 0.f);
        *(float4*)(out + (size_t)node * 64 + c0) = acc;
    }
    if (do_gsum) {
        __shared__ float red4[16 * 64];
        int nl = t >> 4;
        *(float4*)(red4 + nl * 64 + c0) = acc;   // acc==0 for node>=N
        __syncthreads();
        if (t < 64) {
            float s = 0.f;
            #pragma unroll
            for (int k = 0; k < 16; k++) s += red4[k * 64 + t];
            atomicAdd(&gsum[t], s);
        }
    }
}

// ================= head =================

__global__ void final_kernel(const float* __restrict__ h3, const int* __restrict__ sheet_idx,
                             const float* __restrict__ sheet_feat, const float* __restrict__ g_sum,
                             const float* __restrict__ gW1, const float* __restrict__ gb1,
                             const float* __restrict__ gW2, const float* __restrict__ gb2,
                             const float* __restrict__ fW,  const float* __restrict__ fb,
                             const float* __restrict__ qW1, const float* __restrict__ qb1,
                             const float* __restrict__ qW2, const float* __restrict__ qb2,
                             float* __restrict__ out, int N, int L) {
    int s = blockIdx.x, t = threadIdx.x;
    __shared__ float red[256];
    __shared__ float semb[64];
    __shared__ float geoh[64];
    __shared__ float geo[64];
    __shared__ float hq[128];   // [fused(0..63) | g_emb(64..127)]
    int c = t & 63, jg = t >> 6;
    float acc = 0.0f;
    for (int j = jg; j < L; j += 4) {
        int node = sheet_idx[s * L + j];
        acc += h3[(size_t)node * 64 + c];
    }
    red[t] = acc;
    __syncthreads();
    if (t < 64) {
        semb[t] = (red[t] + red[t + 64] + red[t + 128] + red[t + 192]) / (float)L;
        hq[64 + t] = g_sum[t] / (float)N;
        float a = gb1[t];
        #pragma unroll
        for (int k = 0; k < FEAT; k++) a += sheet_feat[s * FEAT + k] * gW1[k * 64 + t];
        geoh[t] = fmaxf(a, 0.0f);
    }
    __syncthreads();
    if (t < 64) {
        float a = gb2[t];
        for (int k = 0; k < 64; k++) a += geoh[k] * gW2[k * 64 + t];
        geo[t] = a;                                   // no relu on geo output
    }
    __syncthreads();
    if (t < 64) {
        float a = fb[t];
        for (int k = 0; k < 64; k++) a += semb[k] * fW[k * 64 + t];
        for (int k = 0; k < 64; k++) a += geo[k]  * fW[(64 + k) * 64 + t];
        hq[t] = fmaxf(a, 0.0f);                       // fused
    }
    __syncthreads();
    float q = 0.0f;
    if (t < 64) {
        float a = qb1[t];
        for (int k = 0; k < 128; k++) a += hq[k] * qW1[k * 64 + t];
        a = fmaxf(a, 0.0f);
        q = a * qW2[t];
        for (int off = 32; off > 0; off >>= 1) q += __shfl_down(q, off, 64);
        if (t == 0) out[s] = q + qb2[0];
    }
}

extern "C" void kernel_launch(void* const* d_in, const int* in_sizes, int n_in,
                              void* d_out, int out_size, void* d_ws, size_t ws_size,
                              hipStream_t stream) {
    const float* x          = (const float*)d_in[0];
    const int*   edge       = (const int*)d_in[1];     // [2, E]: src row then dst row
    const int*   sheet_idx  = (const int*)d_in[3];
    const float* sheet_feat = (const float*)d_in[4];
    const float* W1 = (const float*)d_in[5];  const float* b1 = (const float*)d_in[6];
    const float* W2 = (const float*)d_in[7];  const float* b2 = (const float*)d_in[8];
    const float* W3 = (const float*)d_in[9];  const float* b3 = (const float*)d_in[10];
    const float* gW1 = (const float*)d_in[11]; const float* gb1 = (const float*)d_in[12];
    const float* gW2 = (const float*)d_in[13]; const float* gb2 = (const float*)d_in[14];
    const float* fW  = (const float*)d_in[15]; const float* fb  = (const float*)d_in[16];
    const float* qW1 = (const float*)d_in[17]; const float* qb1 = (const float*)d_in[18];
    const float* qW2 = (const float*)d_in[19]; const float* qb2 = (const float*)d_in[20];
    float* out = (float*)d_out;

    int N = in_sizes[2];            // 50000
    int E = in_sizes[1] / 2;        // 800000
    int S = in_sizes[4] / FEAT;     // 256
    int L = in_sizes[3] / S;        // 128

    int nb = (N + 255) / 256;       // scan blocks (<= 256 required; 196 here)

    // ---- workspace layout ----
    char* p = (char*)d_ws;
    int*   cnt     = (int*)p;              p += (size_t)N * 4;
    int*   row_ptr = (int*)p;              p += (size_t)(N + 1) * 4;
    int*   cursor  = (int*)p;              p += (size_t)N * 4;
    int*   bsum    = (int*)p;              p += 256 * 4;
    int*   csr_src = (int*)p;              p += (size_t)E * 4;
    float* csr_w   = (float*)p;            p += (size_t)E * 4;
    float* dinv    = (float*)p;            p += (size_t)N * 4;
    float* gsum    = (float*)p;            p += 64 * 4;
    float* bufA    = (float*)p;            p += (size_t)N * 64 * 4;
    float* bufB    = (float*)p;            /* N*64*4 */

    hipMemsetAsync(cnt, 0, (size_t)N * 4, stream);
    hipMemsetAsync(gsum, 0, 64 * 4, stream);

    const int* src = edge;
    const int* dst = edge + E;

    int gE = (E + 255) / 256;
    int gN = (N + 255) / 256;
    int gMM = (N + 15) / 16;
    int gGA = (N + 15) / 16;

    // CSR build
    hist_kernel<<<gE, 256, 0, stream>>>(dst, cnt, E);
    dinv_kernel<<<gN, 256, 0, stream>>>(cnt, dinv, N);
    bsum_kernel<<<nb, 256, 0, stream>>>(cnt, bsum, N);
    bscan_kernel<<<1, 256, 0, stream>>>(bsum, row_ptr, nb, N);
    chunk_scan_kernel<<<nb, 256, 0, stream>>>(cnt, bsum, row_ptr, cursor, N);
    scatter_kernel<<<gE, 256, 0, stream>>>(src, dst, dinv, cursor, csr_src, csr_w, E);

    // layer 1: x -> bufB (hw), gather -> bufA
    gcn_matmul<<<gMM, 256, 0, stream>>>(x, W1, bufB, N, FEAT);
    gather_agg<<<gGA, 256, 0, stream>>>(row_ptr, csr_src, csr_w, bufB, dinv, b1, bufA, gsum, N, 0);

    // layer 2: bufA -> bufB (hw), gather -> bufA
    gcn_matmul<<<gMM, 256, 0, stream>>>(bufA, W2, bufB, N, HID);
    gather_agg<<<gGA, 256, 0, stream>>>(row_ptr, csr_src, csr_w, bufB, dinv, b2, bufA, gsum, N, 0);

    // layer 3: bufA -> bufB (hw), gather -> bufA (h3), accumulate gsum
    gcn_matmul<<<gMM, 256, 0, stream>>>(bufA, W3, bufB, N, HID);
    gather_agg<<<gGA, 256, 0, stream>>>(row_ptr, csr_src, csr_w, bufB, dinv, b3, bufA, gsum, N, 1);

    final_kernel<<<S, 256, 0, stream>>>(bufA, sheet_idx, sheet_feat, gsum,
                                        gW1, gb1, gW2, gb2, fW, fb,
                                        qW1, qb1, qW2, qb2, out, N, L);
}

// Round 3
// 406.827 us; speedup vs baseline: 6.0387x; 1.1964x over previous
//
#include <hip/hip_runtime.h>

#define HID 64
#define FEAT 10

// ================= CSR build =================

__global__ void hist_kernel(const int* __restrict__ dst, int* __restrict__ cnt, int E) {
    int e = blockIdx.x * 256 + threadIdx.x;
    if (e < E) atomicAdd(&cnt[dst[e]], 1);
}

__global__ void dinv_kernel(const int* __restrict__ cnt, float* __restrict__ dinv, int N) {
    int i = blockIdx.x * 256 + threadIdx.x;
    if (i < N) dinv[i] = rsqrtf((float)cnt[i] + 1.0f);
}

// per-block partial sums of cnt (256 elems per block)
__global__ void bsum_kernel(const int* __restrict__ cnt, int* __restrict__ bsum, int N) {
    __shared__ int lds[256];
    int i = blockIdx.x * 256 + threadIdx.x;
    lds[threadIdx.x] = (i < N) ? cnt[i] : 0;
    __syncthreads();
    for (int off = 128; off > 0; off >>= 1) {
        if (threadIdx.x < off) lds[threadIdx.x] += lds[threadIdx.x + off];
        __syncthreads();
    }
    if (threadIdx.x == 0) bsum[blockIdx.x] = lds[0];
}

// single block: exclusive scan of bsum[nb] in place; row_ptr[N] = total
__global__ void bscan_kernel(int* __restrict__ bsum, int* __restrict__ row_ptr, int nb, int N) {
    __shared__ int lds[256];
    int t = threadIdx.x;
    int v = (t < nb) ? bsum[t] : 0;
    lds[t] = v;
    __syncthreads();
    for (int off = 1; off < 256; off <<= 1) {
        int a = lds[t];
        int b = (t >= off) ? lds[t - off] : 0;
        __syncthreads();
        lds[t] = a + b;
        __syncthreads();
    }
    if (t < nb) bsum[t] = lds[t] - v;            // exclusive
    if (t == 0) row_ptr[N] = lds[255];           // total == E
}

// per-block: exclusive scan within chunk + block offset -> row_ptr, cursor
__global__ void chunk_scan_kernel(const int* __restrict__ cnt, const int* __restrict__ bsum,
                                  int* __restrict__ row_ptr, int* __restrict__ cursor, int N) {
    __shared__ int lds[256];
    int t = threadIdx.x;
    int i = blockIdx.x * 256 + t;
    int v = (i < N) ? cnt[i] : 0;
    lds[t] = v;
    __syncthreads();
    for (int off = 1; off < 256; off <<= 1) {
        int a = lds[t];
        int b = (t >= off) ? lds[t - off] : 0;
        __syncthreads();
        lds[t] = a + b;
        __syncthreads();
    }
    if (i < N) {
        int val = bsum[blockIdx.x] + lds[t] - v;
        row_ptr[i] = val;
        cursor[i]  = val;
    }
}

// packed CSR entry: {src, float_bits(weight)}
__global__ void scatter_kernel(const int* __restrict__ src, const int* __restrict__ dst,
                               const float* __restrict__ dinv, int* __restrict__ cursor,
                               int2* __restrict__ csr, int E) {
    int e = blockIdx.x * 256 + threadIdx.x;
    if (e >= E) return;
    int s = src[e], d = dst[e];
    int pos = atomicAdd(&cursor[d], 1);
    csr[pos] = make_int2(s, __float_as_int(dinv[s] * dinv[d]));
}

// ================= GCN layers =================

// hw = h_in @ W. block = 256 threads: 16 nodes x 16 col-groups (float4/thread).
__global__ void gcn_matmul(const float* __restrict__ h_in, const float* __restrict__ W,
                           float* __restrict__ hw, int N, int Fin) {
    __shared__ float sW[64 * 64];
    __shared__ float sH[16 * 65];      // stride 65: kill 4-way bank conflict on row broadcast
    int t = threadIdx.x;
    for (int i = t; i < Fin * 64; i += 256) sW[i] = W[i];
    int node0 = blockIdx.x * 16;
    for (int i = t; i < 16 * Fin; i += 256) {
        int r = i / Fin, k = i - r * Fin;
        int node = node0 + r;
        sH[r * 65 + k] = (node < N) ? h_in[(size_t)node * Fin + k] : 0.0f;
    }
    __syncthreads();
    int r = t >> 4;
    int c0 = (t & 15) * 4;
    int node = node0 + r;
    if (node >= N) return;
    float4 acc = make_float4(0.f, 0.f, 0.f, 0.f);
    const float* hrow = sH + r * 65;
    for (int k = 0; k < Fin; k++) {
        float a = hrow[k];
        float4 w = *(const float4*)(sW + k * 64 + c0);
        acc.x += a * w.x; acc.y += a * w.y; acc.z += a * w.z; acc.w += a * w.w;
    }
    *(float4*)(hw + (size_t)node * 64 + c0) = acc;
}

// out[n] = relu( hw[n]*dinv[n]^2 + sum_{e in CSR[n]} hw[src_e]*w_e + b )
// 16 lanes per node (float4 per lane), 16 nodes per block. 8-wide MLP unroll.
__global__ void gather_agg(const int* __restrict__ row_ptr, const int2* __restrict__ csr,
                           const float* __restrict__ hw,
                           const float* __restrict__ dinv, const float* __restrict__ b,
                           float* __restrict__ out, float* __restrict__ gsum,
                           int N, int do_gsum) {
    int t = threadIdx.x;
    int node = blockIdx.x * 16 + (t >> 4);
    int q = t & 15;
    int c0 = q * 4;
    float4 acc = make_float4(0.f, 0.f, 0.f, 0.f);
    if (node < N) {
        float di = dinv[node];
        float wself = di * di;
        float4 v = *(const float4*)(hw + (size_t)node * 64 + c0);
        acc.x = v.x * wself; acc.y = v.y * wself; acc.z = v.z * wself; acc.w = v.w * wself;
        int i = row_ptr[node], i1 = row_ptr[node + 1];
        for (; i + 8 <= i1; i += 8) {
            int2 e0 = csr[i + 0], e1 = csr[i + 1], e2 = csr[i + 2], e3 = csr[i + 3];
            int2 e4 = csr[i + 4], e5 = csr[i + 5], e6 = csr[i + 6], e7 = csr[i + 7];
            float4 u0 = *(const float4*)(hw + (size_t)e0.x * 64 + c0);
            float4 u1 = *(const float4*)(hw + (size_t)e1.x * 64 + c0);
            float4 u2 = *(const float4*)(hw + (size_t)e2.x * 64 + c0);
            float4 u3 = *(const float4*)(hw + (size_t)e3.x * 64 + c0);
            float4 u4 = *(const float4*)(hw + (size_t)e4.x * 64 + c0);
            float4 u5 = *(const float4*)(hw + (size_t)e5.x * 64 + c0);
            float4 u6 = *(const float4*)(hw + (size_t)e6.x * 64 + c0);
            float4 u7 = *(const float4*)(hw + (size_t)e7.x * 64 + c0);
            float w0 = __int_as_float(e0.y), w1 = __int_as_float(e1.y);
            float w2 = __int_as_float(e2.y), w3 = __int_as_float(e3.y);
            float w4 = __int_as_float(e4.y), w5 = __int_as_float(e5.y);
            float w6 = __int_as_float(e6.y), w7 = __int_as_float(e7.y);
            acc.x += u0.x*w0 + u1.x*w1 + u2.x*w2 + u3.x*w3 + u4.x*w4 + u5.x*w5 + u6.x*w6 + u7.x*w7;
            acc.y += u0.y*w0 + u1.y*w1 + u2.y*w2 + u3.y*w3 + u4.y*w4 + u5.y*w5 + u6.y*w6 + u7.y*w7;
            acc.z += u0.z*w0 + u1.z*w1 + u2.z*w2 + u3.z*w3 + u4.z*w4 + u5.z*w5 + u6.z*w6 + u7.z*w7;
            acc.w += u0.w*w0 + u1.w*w1 + u2.w*w2 + u3.w*w3 + u4.w*w4 + u5.w*w5 + u6.w*w6 + u7.w*w7;
        }
        for (; i + 4 <= i1; i += 4) {
            int2 e0 = csr[i + 0], e1 = csr[i + 1], e2 = csr[i + 2], e3 = csr[i + 3];
            float4 u0 = *(const float4*)(hw + (size_t)e0.x * 64 + c0);
            float4 u1 = *(const float4*)(hw + (size_t)e1.x * 64 + c0);
            float4 u2 = *(const float4*)(hw + (size_t)e2.x * 64 + c0);
            float4 u3 = *(const float4*)(hw + (size_t)e3.x * 64 + c0);
            float w0 = __int_as_float(e0.y), w1 = __int_as_float(e1.y);
            float w2 = __int_as_float(e2.y), w3 = __int_as_float(e3.y);
            acc.x += u0.x*w0 + u1.x*w1 + u2.x*w2 + u3.x*w3;
            acc.y += u0.y*w0 + u1.y*w1 + u2.y*w2 + u3.y*w3;
            acc.z += u0.z*w0 + u1.z*w1 + u2.z*w2 + u3.z*w3;
            acc.w += u0.w*w0 + u1.w*w1 + u2.w*w2 + u3.w*w3;
        }
        for (; i < i1; i++) {
            int2 e0 = csr[i];
            float w0 = __int_as_float(e0.y);
            float4 u0 = *(const float4*)(hw + (size_t)e0.x * 64 + c0);
            acc.x += u0.x * w0; acc.y += u0.y * w0; acc.z += u0.z * w0; acc.w += u0.w * w0;
        }
        const float4 bb = *(const float4*)(b + c0);
        acc.x = fmaxf(acc.x + bb.x, 0.f);
        acc.y = fmaxf(acc.y + bb.y, 0.f);
        acc.z = fmaxf(acc.z + bb.z, 0.f);
        acc.w = fmaxf(acc.w + bb.w, 0.f);
        *(float4*)(out + (size_t)node * 64 + c0) = acc;
    }
    if (do_gsum) {
        __shared__ float red4[16 * 64];
        int nl = t >> 4;
        *(float4*)(red4 + nl * 64 + c0) = acc;   // acc==0 for node>=N
        __syncthreads();
        if (t < 64) {
            float s = 0.f;
            #pragma unroll
            for (int k = 0; k < 16; k++) s += red4[k * 64 + t];
            atomicAdd(&gsum[t], s);
        }
    }
}

// ================= head =================

__global__ void final_kernel(const float* __restrict__ h3, const int* __restrict__ sheet_idx,
                             const float* __restrict__ sheet_feat, const float* __restrict__ g_sum,
                             const float* __restrict__ gW1, const float* __restrict__ gb1,
                             const float* __restrict__ gW2, const float* __restrict__ gb2,
                             const float* __restrict__ fW,  const float* __restrict__ fb,
                             const float* __restrict__ qW1, const float* __restrict__ qb1,
                             const float* __restrict__ qW2, const float* __restrict__ qb2,
                             float* __restrict__ out, int N, int L) {
    int s = blockIdx.x, t = threadIdx.x;
    __shared__ float red[256];
    __shared__ float semb[64];
    __shared__ float geoh[64];
    __shared__ float geo[64];
    __shared__ float hq[128];   // [fused(0..63) | g_emb(64..127)]
    int c = t & 63, jg = t >> 6;
    float acc = 0.0f;
    for (int j = jg; j < L; j += 4) {
        int node = sheet_idx[s * L + j];
        acc += h3[(size_t)node * 64 + c];
    }
    red[t] = acc;
    __syncthreads();
    if (t < 64) {
        semb[t] = (red[t] + red[t + 64] + red[t + 128] + red[t + 192]) / (float)L;
        hq[64 + t] = g_sum[t] / (float)N;
        float a = gb1[t];
        #pragma unroll
        for (int k = 0; k < FEAT; k++) a += sheet_feat[s * FEAT + k] * gW1[k * 64 + t];
        geoh[t] = fmaxf(a, 0.0f);
    }
    __syncthreads();
    if (t < 64) {
        float a = gb2[t];
        for (int k = 0; k < 64; k++) a += geoh[k] * gW2[k * 64 + t];
        geo[t] = a;                                   // no relu on geo output
    }
    __syncthreads();
    if (t < 64) {
        float a = fb[t];
        for (int k = 0; k < 64; k++) a += semb[k] * fW[k * 64 + t];
        for (int k = 0; k < 64; k++) a += geo[k]  * fW[(64 + k) * 64 + t];
        hq[t] = fmaxf(a, 0.0f);                       // fused
    }
    __syncthreads();
    float q = 0.0f;
    if (t < 64) {
        float a = qb1[t];
        for (int k = 0; k < 128; k++) a += hq[k] * qW1[k * 64 + t];
        a = fmaxf(a, 0.0f);
        q = a * qW2[t];
        for (int off = 32; off > 0; off >>= 1) q += __shfl_down(q, off, 64);
        if (t == 0) out[s] = q + qb2[0];
    }
}

extern "C" void kernel_launch(void* const* d_in, const int* in_sizes, int n_in,
                              void* d_out, int out_size, void* d_ws, size_t ws_size,
                              hipStream_t stream) {
    const float* x          = (const float*)d_in[0];
    const int*   edge       = (const int*)d_in[1];     // [2, E]: src row then dst row
    const int*   sheet_idx  = (const int*)d_in[3];
    const float* sheet_feat = (const float*)d_in[4];
    const float* W1 = (const float*)d_in[5];  const float* b1 = (const float*)d_in[6];
    const float* W2 = (const float*)d_in[7];  const float* b2 = (const float*)d_in[8];
    const float* W3 = (const float*)d_in[9];  const float* b3 = (const float*)d_in[10];
    const float* gW1 = (const float*)d_in[11]; const float* gb1 = (const float*)d_in[12];
    const float* gW2 = (const float*)d_in[13]; const float* gb2 = (const float*)d_in[14];
    const float* fW  = (const float*)d_in[15]; const float* fb  = (const float*)d_in[16];
    const float* qW1 = (const float*)d_in[17]; const float* qb1 = (const float*)d_in[18];
    const float* qW2 = (const float*)d_in[19]; const float* qb2 = (const float*)d_in[20];
    float* out = (float*)d_out;

    int N = in_sizes[2];            // 50000
    int E = in_sizes[1] / 2;        // 800000
    int S = in_sizes[4] / FEAT;     // 256
    int L = in_sizes[3] / S;        // 128

    int nb = (N + 255) / 256;       // scan blocks (196 <= 256 required)

    // ---- workspace layout (csr first: needs 8-byte alignment) ----
    char* p = (char*)d_ws;
    int2*  csr     = (int2*)p;             p += (size_t)E * 8;
    float* bufA    = (float*)p;            p += (size_t)N * 64 * 4;
    float* bufB    = (float*)p;            p += (size_t)N * 64 * 4;
    int*   cnt     = (int*)p;              p += (size_t)N * 4;
    int*   row_ptr = (int*)p;              p += (size_t)(N + 1) * 4;
    int*   cursor  = (int*)p;              p += (size_t)N * 4;
    int*   bsum    = (int*)p;              p += 256 * 4;
    float* dinv    = (float*)p;            p += (size_t)N * 4;
    float* gsum    = (float*)p;            /* 64*4 */

    hipMemsetAsync(cnt, 0, (size_t)N * 4, stream);
    hipMemsetAsync(gsum, 0, 64 * 4, stream);

    const int* src = edge;
    const int* dst = edge + E;

    int gE = (E + 255) / 256;
    int gN = (N + 255) / 256;
    int gMM = (N + 15) / 16;
    int gGA = (N + 15) / 16;

    // CSR build
    hist_kernel<<<gE, 256, 0, stream>>>(dst, cnt, E);
    dinv_kernel<<<gN, 256, 0, stream>>>(cnt, dinv, N);
    bsum_kernel<<<nb, 256, 0, stream>>>(cnt, bsum, N);
    bscan_kernel<<<1, 256, 0, stream>>>(bsum, row_ptr, nb, N);
    chunk_scan_kernel<<<nb, 256, 0, stream>>>(cnt, bsum, row_ptr, cursor, N);
    scatter_kernel<<<gE, 256, 0, stream>>>(src, dst, dinv, cursor, csr, E);

    // layer 1: x -> bufB (hw), gather -> bufA
    gcn_matmul<<<gMM, 256, 0, stream>>>(x, W1, bufB, N, FEAT);
    gather_agg<<<gGA, 256, 0, stream>>>(row_ptr, csr, bufB, dinv, b1, bufA, gsum, N, 0);

    // layer 2: bufA -> bufB (hw), gather -> bufA
    gcn_matmul<<<gMM, 256, 0, stream>>>(bufA, W2, bufB, N, HID);
    gather_agg<<<gGA, 256, 0, stream>>>(row_ptr, csr, bufB, dinv, b2, bufA, gsum, N, 0);

    // layer 3: bufA -> bufB (hw), gather -> bufA (h3), accumulate gsum
    gcn_matmul<<<gMM, 256, 0, stream>>>(bufA, W3, bufB, N, HID);
    gather_agg<<<gGA, 256, 0, stream>>>(row_ptr, csr, bufB, dinv, b3, bufA, gsum, N, 1);

    final_kernel<<<S, 256, 0, stream>>>(bufA, sheet_idx, sheet_feat, gsum,
                                        gW1, gb1, gW2, gb2, fW, fb,
                                        qW1, qb1, qW2, qb2, out, N, L);
}

// Round 4
// 326.580 us; speedup vs baseline: 7.5225x; 1.2457x over previous
//
#include <hip/hip_runtime.h>

#define HID 64
#define FEAT 10

// ---------- helpers ----------
__device__ inline unsigned short f2bf(float f) {          // fp32 -> bf16 RNE
    unsigned u = __float_as_uint(f);
    unsigned r = (u + 0x7fffu + ((u >> 16) & 1u)) >> 16;
    return (unsigned short)r;
}
__device__ inline void bf8_fma(float* acc, uint4 u, float w) {
    acc[0] += __uint_as_float(u.x << 16) * w;
    acc[1] += __uint_as_float(u.x & 0xffff0000u) * w;
    acc[2] += __uint_as_float(u.y << 16) * w;
    acc[3] += __uint_as_float(u.y & 0xffff0000u) * w;
    acc[4] += __uint_as_float(u.z << 16) * w;
    acc[5] += __uint_as_float(u.z & 0xffff0000u) * w;
    acc[6] += __uint_as_float(u.w << 16) * w;
    acc[7] += __uint_as_float(u.w & 0xffff0000u) * w;
}

// ================= CSR build =================

__global__ void hist_kernel(const int* __restrict__ dst, int* __restrict__ cnt, int E) {
    int e = blockIdx.x * 256 + threadIdx.x;
    if (e < E) atomicAdd(&cnt[dst[e]], 1);
}

__global__ void dinv_kernel(const int* __restrict__ cnt, float* __restrict__ dinv, int N) {
    int i = blockIdx.x * 256 + threadIdx.x;
    if (i < N) dinv[i] = rsqrtf((float)cnt[i] + 1.0f);
}

__global__ void bsum_kernel(const int* __restrict__ cnt, int* __restrict__ bsum, int N) {
    __shared__ int lds[256];
    int i = blockIdx.x * 256 + threadIdx.x;
    lds[threadIdx.x] = (i < N) ? cnt[i] : 0;
    __syncthreads();
    for (int off = 128; off > 0; off >>= 1) {
        if (threadIdx.x < off) lds[threadIdx.x] += lds[threadIdx.x + off];
        __syncthreads();
    }
    if (threadIdx.x == 0) bsum[blockIdx.x] = lds[0];
}

__global__ void bscan_kernel(int* __restrict__ bsum, int* __restrict__ row_ptr, int nb, int N) {
    __shared__ int lds[256];
    int t = threadIdx.x;
    int v = (t < nb) ? bsum[t] : 0;
    lds[t] = v;
    __syncthreads();
    for (int off = 1; off < 256; off <<= 1) {
        int a = lds[t];
        int b = (t >= off) ? lds[t - off] : 0;
        __syncthreads();
        lds[t] = a + b;
        __syncthreads();
    }
    if (t < nb) bsum[t] = lds[t] - v;
    if (t == 0) row_ptr[N] = lds[255];
}

__global__ void chunk_scan_kernel(const int* __restrict__ cnt, const int* __restrict__ bsum,
                                  int* __restrict__ row_ptr, int* __restrict__ cursor, int N) {
    __shared__ int lds[256];
    int t = threadIdx.x;
    int i = blockIdx.x * 256 + t;
    int v = (i < N) ? cnt[i] : 0;
    lds[t] = v;
    __syncthreads();
    for (int off = 1; off < 256; off <<= 1) {
        int a = lds[t];
        int b = (t >= off) ? lds[t - off] : 0;
        __syncthreads();
        lds[t] = a + b;
        __syncthreads();
    }
    if (i < N) {
        int val = bsum[blockIdx.x] + lds[t] - v;
        row_ptr[i] = val;
        cursor[i]  = val;
    }
}

__global__ void scatter_kernel(const int* __restrict__ src, const int* __restrict__ dst,
                               const float* __restrict__ dinv, int* __restrict__ cursor,
                               int2* __restrict__ csr, int E) {
    int e = blockIdx.x * 256 + threadIdx.x;
    if (e >= E) return;
    int s = src[e], d = dst[e];
    int pos = atomicAdd(&cursor[d], 1);
    csr[pos] = make_int2(s, __float_as_int(dinv[s] * dinv[d]));
}

// ================= layer 1: aggregate raw x (10-wide), then matmul =================

// aggx[n][q] = wself*x[n][q] + sum_e w_e * x[src_e][q]   (16 lanes/node, lanes 10..15 idle on loads)
__global__ void gather_x(const int* __restrict__ row_ptr, const int2* __restrict__ csr,
                         const float* __restrict__ x, const float* __restrict__ dinv,
                         float* __restrict__ aggx, int N) {
    int t = threadIdx.x;
    int node = blockIdx.x * 16 + (t >> 4);
    int q = t & 15;
    if (node >= N) return;
    float di = dinv[node];
    float acc = 0.0f;
    if (q < FEAT) acc = di * di * x[(size_t)node * FEAT + q];
    int i = row_ptr[node], i1 = row_ptr[node + 1];
    for (; i + 4 <= i1; i += 4) {
        int2 e0 = csr[i], e1 = csr[i + 1], e2 = csr[i + 2], e3 = csr[i + 3];
        if (q < FEAT) {
            float v0 = x[(size_t)e0.x * FEAT + q];
            float v1 = x[(size_t)e1.x * FEAT + q];
            float v2 = x[(size_t)e2.x * FEAT + q];
            float v3 = x[(size_t)e3.x * FEAT + q];
            acc += v0 * __int_as_float(e0.y) + v1 * __int_as_float(e1.y)
                 + v2 * __int_as_float(e2.y) + v3 * __int_as_float(e3.y);
        }
    }
    for (; i < i1; i++) {
        int2 e0 = csr[i];
        if (q < FEAT) acc += x[(size_t)e0.x * FEAT + q] * __int_as_float(e0.y);
    }
    if (q < FEAT) aggx[(size_t)node * FEAT + q] = acc;
}

// h1 = relu(aggx @ W1 + b1), fp32 out. 64 nodes/block, 4 nodes x 4 cols per thread.
__global__ void gcn_matmul1(const float* __restrict__ aggx, const float* __restrict__ W1,
                            const float* __restrict__ b1, float* __restrict__ h1, int N) {
    __shared__ float sW[FEAT * 64];
    __shared__ float sH[64 * (FEAT + 1)];
    int t = threadIdx.x;
    int node0 = blockIdx.x * 64;
    for (int i = t; i < FEAT * 64; i += 256) sW[i] = W1[i];
    for (int i = t; i < 64 * FEAT; i += 256) {
        int r = i / FEAT, k = i - r * FEAT;
        int node = node0 + r;
        sH[r * (FEAT + 1) + k] = (node < N) ? aggx[(size_t)node * FEAT + k] : 0.0f;
    }
    __syncthreads();
    int c0 = (t & 15) * 4;
    int rbase = (t >> 4) * 4;
    float4 a0 = {0,0,0,0}, a1 = {0,0,0,0}, a2 = {0,0,0,0}, a3 = {0,0,0,0};
    for (int k = 0; k < FEAT; k++) {
        float4 w = *(const float4*)(sW + k * 64 + c0);
        float h0 = sH[(rbase + 0) * (FEAT + 1) + k];
        float h1v = sH[(rbase + 1) * (FEAT + 1) + k];
        float h2 = sH[(rbase + 2) * (FEAT + 1) + k];
        float h3 = sH[(rbase + 3) * (FEAT + 1) + k];
        a0.x += h0 * w.x; a0.y += h0 * w.y; a0.z += h0 * w.z; a0.w += h0 * w.w;
        a1.x += h1v * w.x; a1.y += h1v * w.y; a1.z += h1v * w.z; a1.w += h1v * w.w;
        a2.x += h2 * w.x; a2.y += h2 * w.y; a2.z += h2 * w.z; a2.w += h2 * w.w;
        a3.x += h3 * w.x; a3.y += h3 * w.y; a3.z += h3 * w.z; a3.w += h3 * w.w;
    }
    float4 bb = *(const float4*)(b1 + c0);
    float4 accs[4] = {a0, a1, a2, a3};
    for (int rr = 0; rr < 4; rr++) {
        int node = node0 + rbase + rr;
        if (node >= N) break;
        float4 v = accs[rr];
        v.x = fmaxf(v.x + bb.x, 0.f); v.y = fmaxf(v.y + bb.y, 0.f);
        v.z = fmaxf(v.z + bb.z, 0.f); v.w = fmaxf(v.w + bb.w, 0.f);
        *(float4*)(h1 + (size_t)node * 64 + c0) = v;
    }
}

// ================= layers 2/3: matmul fp32->bf16, gather bf16 =================

// hwb = bf16(h_in @ W). 64 nodes/block, 4 nodes x 4 cols per thread, W float4 amortized.
__global__ void gcn_matmul64(const float* __restrict__ h_in, const float* __restrict__ W,
                             unsigned short* __restrict__ hwb, int N) {
    __shared__ float sW[64 * 64];
    __shared__ float sH[64 * 65];
    int t = threadIdx.x;
    int node0 = blockIdx.x * 64;
    for (int i = t * 4; i < 4096; i += 1024)
        *(float4*)(sW + i) = *(const float4*)(W + i);
    for (int i = t; i < 4096; i += 256) {
        int r = i >> 6, k = i & 63;
        int node = node0 + r;
        sH[r * 65 + k] = (node < N) ? h_in[(size_t)node * 64 + k] : 0.0f;
    }
    __syncthreads();
    int c0 = (t & 15) * 4;
    int rbase = (t >> 4) * 4;
    float4 a0 = {0,0,0,0}, a1 = {0,0,0,0}, a2 = {0,0,0,0}, a3 = {0,0,0,0};
    for (int k = 0; k < 64; k++) {
        float4 w = *(const float4*)(sW + k * 64 + c0);
        float h0 = sH[(rbase + 0) * 65 + k];
        float h1v = sH[(rbase + 1) * 65 + k];
        float h2 = sH[(rbase + 2) * 65 + k];
        float h3 = sH[(rbase + 3) * 65 + k];
        a0.x += h0 * w.x; a0.y += h0 * w.y; a0.z += h0 * w.z; a0.w += h0 * w.w;
        a1.x += h1v * w.x; a1.y += h1v * w.y; a1.z += h1v * w.z; a1.w += h1v * w.w;
        a2.x += h2 * w.x; a2.y += h2 * w.y; a2.z += h2 * w.z; a2.w += h2 * w.w;
        a3.x += h3 * w.x; a3.y += h3 * w.y; a3.z += h3 * w.z; a3.w += h3 * w.w;
    }
    float4 accs[4] = {a0, a1, a2, a3};
    for (int rr = 0; rr < 4; rr++) {
        int node = node0 + rbase + rr;
        if (node >= N) break;
        float4 v = accs[rr];
        ushort4 o;
        o.x = f2bf(v.x); o.y = f2bf(v.y); o.z = f2bf(v.z); o.w = f2bf(v.w);
        *(ushort4*)(hwb + (size_t)node * 64 + c0) = o;
    }
}

// out[n] = relu( bf16dec(hwb[n])*wself + sum_e bf16dec(hwb[src_e])*w_e + b ), fp32 out.
// 32 nodes/block, 8 lanes/node, 8 cols (16B bf16) per lane. 8-wide MLP unroll.
__global__ void gather_bf(const int* __restrict__ row_ptr, const int2* __restrict__ csr,
                          const unsigned short* __restrict__ hwb,
                          const float* __restrict__ dinv, const float* __restrict__ b,
                          float* __restrict__ out, float* __restrict__ gsum,
                          int N, int do_gsum) {
    int t = threadIdx.x;
    int nl = t >> 3;
    int node = blockIdx.x * 32 + nl;
    int q = t & 7;
    int c0 = q * 8;
    float acc[8] = {0.f, 0.f, 0.f, 0.f, 0.f, 0.f, 0.f, 0.f};
    if (node < N) {
        float di = dinv[node];
        uint4 sv = *(const uint4*)(hwb + (size_t)node * 64 + c0);
        bf8_fma(acc, sv, di * di);
        int i = row_ptr[node], i1 = row_ptr[node + 1];
        for (; i + 8 <= i1; i += 8) {
            int2 e0 = csr[i + 0], e1 = csr[i + 1], e2 = csr[i + 2], e3 = csr[i + 3];
            int2 e4 = csr[i + 4], e5 = csr[i + 5], e6 = csr[i + 6], e7 = csr[i + 7];
            uint4 u0 = *(const uint4*)(hwb + (size_t)e0.x * 64 + c0);
            uint4 u1 = *(const uint4*)(hwb + (size_t)e1.x * 64 + c0);
            uint4 u2 = *(const uint4*)(hwb + (size_t)e2.x * 64 + c0);
            uint4 u3 = *(const uint4*)(hwb + (size_t)e3.x * 64 + c0);
            uint4 u4 = *(const uint4*)(hwb + (size_t)e4.x * 64 + c0);
            uint4 u5 = *(const uint4*)(hwb + (size_t)e5.x * 64 + c0);
            uint4 u6 = *(const uint4*)(hwb + (size_t)e6.x * 64 + c0);
            uint4 u7 = *(const uint4*)(hwb + (size_t)e7.x * 64 + c0);
            bf8_fma(acc, u0, __int_as_float(e0.y));
            bf8_fma(acc, u1, __int_as_float(e1.y));
            bf8_fma(acc, u2, __int_as_float(e2.y));
            bf8_fma(acc, u3, __int_as_float(e3.y));
            bf8_fma(acc, u4, __int_as_float(e4.y));
            bf8_fma(acc, u5, __int_as_float(e5.y));
            bf8_fma(acc, u6, __int_as_float(e6.y));
            bf8_fma(acc, u7, __int_as_float(e7.y));
        }
        for (; i + 4 <= i1; i += 4) {
            int2 e0 = csr[i + 0], e1 = csr[i + 1], e2 = csr[i + 2], e3 = csr[i + 3];
            uint4 u0 = *(const uint4*)(hwb + (size_t)e0.x * 64 + c0);
            uint4 u1 = *(const uint4*)(hwb + (size_t)e1.x * 64 + c0);
            uint4 u2 = *(const uint4*)(hwb + (size_t)e2.x * 64 + c0);
            uint4 u3 = *(const uint4*)(hwb + (size_t)e3.x * 64 + c0);
            bf8_fma(acc, u0, __int_as_float(e0.y));
            bf8_fma(acc, u1, __int_as_float(e1.y));
            bf8_fma(acc, u2, __int_as_float(e2.y));
            bf8_fma(acc, u3, __int_as_float(e3.y));
        }
        for (; i < i1; i++) {
            int2 e0 = csr[i];
            uint4 u0 = *(const uint4*)(hwb + (size_t)e0.x * 64 + c0);
            bf8_fma(acc, u0, __int_as_float(e0.y));
        }
        float4 o0, o1;
        const float4 bb0 = *(const float4*)(b + c0);
        const float4 bb1 = *(const float4*)(b + c0 + 4);
        o0.x = fmaxf(acc[0] + bb0.x, 0.f); o0.y = fmaxf(acc[1] + bb0.y, 0.f);
        o0.z = fmaxf(acc[2] + bb0.z, 0.f); o0.w = fmaxf(acc[3] + bb0.w, 0.f);
        o1.x = fmaxf(acc[4] + bb1.x, 0.f); o1.y = fmaxf(acc[5] + bb1.y, 0.f);
        o1.z = fmaxf(acc[6] + bb1.z, 0.f); o1.w = fmaxf(acc[7] + bb1.w, 0.f);
        *(float4*)(out + (size_t)node * 64 + c0)     = o0;
        *(float4*)(out + (size_t)node * 64 + c0 + 4) = o1;
        acc[0]=o0.x; acc[1]=o0.y; acc[2]=o0.z; acc[3]=o0.w;
        acc[4]=o1.x; acc[5]=o1.y; acc[6]=o1.z; acc[7]=o1.w;
    }
    if (do_gsum) {
        __shared__ float red[32 * 64];
        if (node < N) {
            for (int j = 0; j < 8; j++) red[nl * 64 + c0 + j] = acc[j];
        } else {
            for (int j = 0; j < 8; j++) red[nl * 64 + c0 + j] = 0.f;
        }
        __syncthreads();
        if (t < 64) {
            float s = 0.f;
            #pragma unroll
            for (int k = 0; k < 32; k++) s += red[k * 64 + t];
            atomicAdd(&gsum[t], s);
        }
    }
}

// ================= head =================

__global__ void final_kernel(const float* __restrict__ h3, const int* __restrict__ sheet_idx,
                             const float* __restrict__ sheet_feat, const float* __restrict__ g_sum,
                             const float* __restrict__ gW1, const float* __restrict__ gb1,
                             const float* __restrict__ gW2, const float* __restrict__ gb2,
                             const float* __restrict__ fW,  const float* __restrict__ fb,
                             const float* __restrict__ qW1, const float* __restrict__ qb1,
                             const float* __restrict__ qW2, const float* __restrict__ qb2,
                             float* __restrict__ out, int N, int L) {
    int s = blockIdx.x, t = threadIdx.x;
    __shared__ float red[256];
    __shared__ float semb[64];
    __shared__ float geoh[64];
    __shared__ float geo[64];
    __shared__ float hq[128];
    int c = t & 63, jg = t >> 6;
    float acc = 0.0f;
    for (int j = jg; j < L; j += 4) {
        int node = sheet_idx[s * L + j];
        acc += h3[(size_t)node * 64 + c];
    }
    red[t] = acc;
    __syncthreads();
    if (t < 64) {
        semb[t] = (red[t] + red[t + 64] + red[t + 128] + red[t + 192]) / (float)L;
        hq[64 + t] = g_sum[t] / (float)N;
        float a = gb1[t];
        #pragma unroll
        for (int k = 0; k < FEAT; k++) a += sheet_feat[s * FEAT + k] * gW1[k * 64 + t];
        geoh[t] = fmaxf(a, 0.0f);
    }
    __syncthreads();
    if (t < 64) {
        float a = gb2[t];
        for (int k = 0; k < 64; k++) a += geoh[k] * gW2[k * 64 + t];
        geo[t] = a;
    }
    __syncthreads();
    if (t < 64) {
        float a = fb[t];
        for (int k = 0; k < 64; k++) a += semb[k] * fW[k * 64 + t];
        for (int k = 0; k < 64; k++) a += geo[k]  * fW[(64 + k) * 64 + t];
        hq[t] = fmaxf(a, 0.0f);
    }
    __syncthreads();
    float q = 0.0f;
    if (t < 64) {
        float a = qb1[t];
        for (int k = 0; k < 128; k++) a += hq[k] * qW1[k * 64 + t];
        a = fmaxf(a, 0.0f);
        q = a * qW2[t];
        for (int off = 32; off > 0; off >>= 1) q += __shfl_down(q, off, 64);
        if (t == 0) out[s] = q + qb2[0];
    }
}

extern "C" void kernel_launch(void* const* d_in, const int* in_sizes, int n_in,
                              void* d_out, int out_size, void* d_ws, size_t ws_size,
                              hipStream_t stream) {
    const float* x          = (const float*)d_in[0];
    const int*   edge       = (const int*)d_in[1];
    const int*   sheet_idx  = (const int*)d_in[3];
    const float* sheet_feat = (const float*)d_in[4];
    const float* W1 = (const float*)d_in[5];  const float* b1 = (const float*)d_in[6];
    const float* W2 = (const float*)d_in[7];  const float* b2 = (const float*)d_in[8];
    const float* W3 = (const float*)d_in[9];  const float* b3 = (const float*)d_in[10];
    const float* gW1 = (const float*)d_in[11]; const float* gb1 = (const float*)d_in[12];
    const float* gW2 = (const float*)d_in[13]; const float* gb2 = (const float*)d_in[14];
    const float* fW  = (const float*)d_in[15]; const float* fb  = (const float*)d_in[16];
    const float* qW1 = (const float*)d_in[17]; const float* qb1 = (const float*)d_in[18];
    const float* qW2 = (const float*)d_in[19]; const float* qb2 = (const float*)d_in[20];
    float* out = (float*)d_out;

    int N = in_sizes[2];            // 50000
    int E = in_sizes[1] / 2;        // 800000
    int S = in_sizes[4] / FEAT;     // 256
    int L = in_sizes[3] / S;        // 128

    int nb = (N + 255) / 256;

    // ---- workspace layout (16B-aligned chunks) ----
    char* p = (char*)d_ws;
    int2*  csr     = (int2*)p;              p += (size_t)E * 8;
    float* hfA     = (float*)p;             p += (size_t)N * 64 * 4;
    float* hfB     = (float*)p;             p += (size_t)N * 64 * 4;
    unsigned short* hwb = (unsigned short*)p; p += (size_t)N * 64 * 2;
    float* aggx    = (float*)p;             p += (size_t)N * FEAT * 4;
    int*   cnt     = (int*)p;               p += (size_t)N * 4;
    int*   row_ptr = (int*)p;               p += (size_t)(N + 1) * 4;
    int*   cursor  = (int*)p;               p += (size_t)N * 4;
    int*   bsum    = (int*)p;               p += 256 * 4;
    float* dinv    = (float*)p;             p += (size_t)N * 4;
    float* gsum    = (float*)p;

    hipMemsetAsync(cnt, 0, (size_t)N * 4, stream);
    hipMemsetAsync(gsum, 0, 64 * 4, stream);

    const int* src = edge;
    const int* dst = edge + E;

    int gE  = (E + 255) / 256;
    int gN  = (N + 255) / 256;
    int gMM = (N + 63) / 64;
    int gGX = (N + 15) / 16;
    int gGB = (N + 31) / 32;

    // CSR build
    hist_kernel<<<gE, 256, 0, stream>>>(dst, cnt, E);
    dinv_kernel<<<gN, 256, 0, stream>>>(cnt, dinv, N);
    bsum_kernel<<<nb, 256, 0, stream>>>(cnt, bsum, N);
    bscan_kernel<<<1, 256, 0, stream>>>(bsum, row_ptr, nb, N);
    chunk_scan_kernel<<<nb, 256, 0, stream>>>(cnt, bsum, row_ptr, cursor, N);
    scatter_kernel<<<gE, 256, 0, stream>>>(src, dst, dinv, cursor, csr, E);

    // layer 1: aggregate x (linear trick), then matmul+bias+relu -> hfA
    gather_x<<<gGX, 256, 0, stream>>>(row_ptr, csr, x, dinv, aggx, N);
    gcn_matmul1<<<gMM, 256, 0, stream>>>(aggx, W1, b1, hfA, N);

    // layer 2: hfA @ W2 -> hwb (bf16); gather -> hfB
    gcn_matmul64<<<gMM, 256, 0, stream>>>(hfA, W2, hwb, N);
    gather_bf<<<gGB, 256, 0, stream>>>(row_ptr, csr, hwb, dinv, b2, hfB, gsum, N, 0);

    // layer 3: hfB @ W3 -> hwb (bf16); gather -> hfA (h3) + gsum
    gcn_matmul64<<<gMM, 256, 0, stream>>>(hfB, W3, hwb, N);
    gather_bf<<<gGB, 256, 0, stream>>>(row_ptr, csr, hwb, dinv, b3, hfA, gsum, N, 1);

    final_kernel<<<S, 256, 0, stream>>>(hfA, sheet_idx, sheet_feat, gsum,
                                        gW1, gb1, gW2, gb2, fW, fb,
                                        qW1, qb1, qW2, qb2, out, N, L);
}